// Round 1
// baseline (28.821 us; speedup 1.0000x reference)
//
#include <hip/hip_runtime.h>

// Problem constants
#define N_MAX       128
#define NODE_VOCAB  128
#define EDGE_VOCAB  16
#define BATCH       256
#define SEQ         8256                   // N_MAX + N_MAX*(N_MAX-1)/2
#define N_EDGES     8128                   // SEQ - N_MAX

// Output layout (flat f32):
//   node_logits [B][N_MAX][NODE_VOCAB]  -> 256*128*128  = 4,194,304
//   edge_logits [B][N_EDGES][EDGE_VOCAB]-> 256*8128*16  = 33,292,288
#define NODE_FLOATS (BATCH * N_MAX * NODE_VOCAB)

// Per-batch float4 counts:
//   edge: 8128*16/4 = 32512  (exactly 127 blocks x 256 threads)
//   node: 128*128/4 = 4096
#define EDGE_F4_PER_B 32512
#define NODE_F4_PER_B 4096

__global__ __launch_bounds__(256)
void fill_logits_kernel(const int* __restrict__ x0,
                        float* __restrict__ out) {
    const int b   = blockIdx.y;
    const int tid = blockIdx.x * 256 + threadIdx.x;   // 0 .. 32511

    const int* __restrict__ xrow = x0 + (size_t)b * SEQ;
    float* __restrict__ out_node = out;
    float* __restrict__ out_edge = out + NODE_FLOATS;

    // ---- edge region: one float4 per thread ----
    {
        const int j  = tid >> 2;            // edge slot 0..8127
        const int v0 = (tid & 3) << 2;      // vocab offset 0,4,8,12
        const int x  = xrow[N_MAX + j];

        float4 v;
        v.x = (x == v0 + 0) ? 100.0f : -100.0f;
        v.y = (x == v0 + 1) ? 100.0f : -100.0f;
        v.z = (x == v0 + 2) ? 100.0f : -100.0f;
        v.w = (x == v0 + 3) ? 100.0f : -100.0f;

        float4* dst = reinterpret_cast<float4*>(
            out_edge + ((size_t)b * N_EDGES + j) * EDGE_VOCAB) + (tid & 3);
        *dst = v;
    }

    // ---- node region: threads 0..4095 also write one float4 ----
    if (tid < NODE_F4_PER_B) {
        const int i  = tid >> 5;            // node slot 0..127
        const int v0 = (tid & 31) << 2;     // vocab offset 0..124
        const int x  = xrow[i];

        float4 v;
        v.x = (x == v0 + 0) ? 100.0f : -100.0f;
        v.y = (x == v0 + 1) ? 100.0f : -100.0f;
        v.z = (x == v0 + 2) ? 100.0f : -100.0f;
        v.w = (x == v0 + 3) ? 100.0f : -100.0f;

        float4* dst = reinterpret_cast<float4*>(
            out_node + ((size_t)b * N_MAX + i) * NODE_VOCAB) + (tid & 31);
        *dst = v;
    }
}

extern "C" void kernel_launch(void* const* d_in, const int* in_sizes, int n_in,
                              void* d_out, int out_size, void* d_ws, size_t ws_size,
                              hipStream_t stream) {
    const int* x0 = (const int*)d_in[0];   // [B, SEQ] int32 (harness converts ints)
    float* out    = (float*)d_out;

    dim3 grid(EDGE_F4_PER_B / 256, BATCH);   // (127, 256)
    fill_logits_kernel<<<grid, 256, 0, stream>>>(x0, out);
}